// Round 6
// baseline (41.657 us; speedup 1.0000x reference)
//
#include <hip/hip_runtime.h>
#include <hip/hip_bf16.h>
#include <math.h>

#define BB 16
#define NN 256
#define LL 1024
#define DD 256

constexpr float LN_EPS = 1e-5f;
constexpr float NEG_SLOPE = 0.01f;

typedef __attribute__((ext_vector_type(8))) short short8;
typedef __attribute__((ext_vector_type(4))) float f32x4;
typedef __attribute__((ext_vector_type(4))) int i32x4;

static __device__ __forceinline__ unsigned cvtpk(float lo, float hi) {
  __hip_bfloat162 h = __float22bfloat162_rn(make_float2(lo, hi));
  union { __hip_bfloat162 h; unsigned u; } v; v.h = h;
  return v.u;
}
static __device__ __forceinline__ short8 pack8(float4 f0, float4 f1) {
  union { i32x4 i; short8 s; } v;
  v.i.x = cvtpk(f0.x, f0.y);
  v.i.y = cvtpk(f0.z, f0.w);
  v.i.z = cvtpk(f1.x, f1.y);
  v.i.w = cvtpk(f1.z, f1.w);
  return v.s;
}
static __device__ __forceinline__ unsigned short f2bf(float f) {
  union { float f; unsigned u; } v; v.f = f;
  unsigned r = v.u + 0x7FFFu + ((v.u >> 16) & 1u);
  return (unsigned short)(r >> 16);
}
static __device__ __forceinline__ float bf2f(unsigned short u) {
  union { unsigned u; float f; } v; v.u = ((unsigned)u) << 16;
  return v.f;
}

// ---------------------------------------------------------------------------
// agemm (MFMA): aT[b][e][l] = sum_d W_nb[e,d]*atom[b,l,d] + b_nb[e]  (bf16)
//   + s2[b][l] from sAT;  blocks 0..15: v1 columns; block0: c0.
// 256 blocks x 1024 thr (16 waves, 4/SIMD). Block tile 256e x 64l.
// Wave w: e in [w*16, w*16+16), all 64 l from LDS atom tile (XOR swizzle).
// XCD swizzle: all blocks of batch b land on XCD b&7.
// ---------------------------------------------------------------------------
__global__ __launch_bounds__(1024) void agemm_kernel(
    const float* __restrict__ atom, const float* __restrict__ W_nb,
    const float* __restrict__ b_nb, const float* __restrict__ W_mol,
    const float* __restrict__ b_mol, const float* __restrict__ align_w,
    const float* __restrict__ align_b, unsigned short* __restrict__ aT,
    float* __restrict__ s2, float* __restrict__ v1c) {
  __shared__ char atile[64 * 256 * 2];      // 32 KB bf16, XOR-swizzled
  __shared__ unsigned short sAT[256 * 68];  // 34 KB
  __shared__ float vp[64][16];

  int t = threadIdx.x;
  int w = t >> 6, lane = t & 63;
  int i = blockIdx.x;
  int x = i & 7, k = i >> 3;
  int b = x + 8 * (k >> 4);          // all blocks of b on XCD b&7
  int l0 = (k & 15) * 64;
  int lo16 = lane & 15, g = lane >> 4;

  // ---- stage atom tile -> LDS bf16 (row r = t>>4, 16 d per thread) ----
  {
    int r = t >> 4, dseg = (t & 15) * 16;
    const float* src = atom + (size_t)(b * LL + l0 + r) * DD + dseg;
    #pragma unroll
    for (int q = 0; q < 2; ++q) {
      float4 f0 = *(const float4*)(src + q * 8);
      float4 f1 = *(const float4*)(src + q * 8 + 4);
      int byte = ((r * 256 + dseg + q * 8) * 2) ^ ((r & 7) << 4);
      *(short8*)(atile + byte) = pack8(f0, f1);
    }
  }

  // ---- side job: v1 columns (blocks 0..15), c0 (block 0) ----
  if (i < 16) {
    int d0 = i * 16;
    int dl = t & 15, eseg = t >> 4;   // 64 segs x 4 e
    float acc = 0.f;
    #pragma unroll
    for (int q = 0; q < 4; ++q) {
      int e = eseg * 4 + q;
      acc += align_w[e] * W_mol[e * DD + d0 + dl];
    }
    vp[eseg][dl] = acc;
    __syncthreads();
    if (t < 16) {
      float s = 0.f;
      #pragma unroll
      for (int q = 0; q < 64; ++q) s += vp[q][t];
      v1c[d0 + t] = s;
    }
    if (i == 0 && w == 1) {
      float s = b_mol[lane] * align_w[lane] +
                b_mol[lane + 64] * align_w[lane + 64] +
                b_mol[lane + 128] * align_w[lane + 128] +
                b_mol[lane + 192] * align_w[lane + 192];
      #pragma unroll
      for (int off = 32; off > 0; off >>= 1) s += __shfl_xor(s, off, 64);
      if (lane == 0) v1c[256] = s + align_b[0];
    }
  }
  __syncthreads();

  // ---- MFMA: wave w -> e rows [w*16, w*16+16), 64 l from LDS ----
  f32x4 acc[4];
  #pragma unroll
  for (int n = 0; n < 4; ++n) acc[n] = f32x4{0.f, 0.f, 0.f, 0.f};

  const float* Ap = W_nb + (size_t)(w * 16 + lo16) * DD + g * 8;

  #pragma unroll 4
  for (int kk = 0; kk < 8; ++kk) {
    float4 f0 = *(const float4*)(Ap + kk * 32);
    float4 f1 = *(const float4*)(Ap + kk * 32 + 4);
    short8 af = pack8(f0, f1);
    #pragma unroll
    for (int n = 0; n < 4; ++n) {
      int l = n * 16 + lo16;
      int byte = ((l * 256 + kk * 32 + g * 8) * 2) ^ ((l & 7) << 4);
      short8 bf = *(const short8*)(atile + byte);
      acc[n] = __builtin_amdgcn_mfma_f32_16x16x32_bf16(af, bf, acc[n], 0, 0, 0);
    }
  }

  // ---- epilogue: +bias, ->bf16 into sAT [256 e][68 l-stride] ----
  {
    int e_lo = w * 16 + g * 4;
    float4 bias = *(const float4*)&b_nb[e_lo];
    #pragma unroll
    for (int n = 0; n < 4; ++n) {
      int l = n * 16 + lo16;
      #pragma unroll
      for (int j = 0; j < 4; ++j) {
        float v = acc[n][j] + ((const float*)&bias)[j];
        sAT[(e_lo + j) * 68 + l] = f2bf(v);
      }
    }
  }
  __syncthreads();

  // ---- s2 from sAT: l = t>>4 (64 rows), e-chunk = (t&15)*16 ----
  {
    int l = t >> 4, ech = (t & 15) * 16;
    float s = 0.f;
    #pragma unroll 8
    for (int q = 0; q < 16; ++q) {
      int e = ech + q;
      s += align_w[DD + e] * bf2f(sAT[e * 68 + l]);
    }
    s += __shfl_xor(s, 1, 64);
    s += __shfl_xor(s, 2, 64);
    s += __shfl_xor(s, 4, 64);
    s += __shfl_xor(s, 8, 64);
    if ((t & 15) == 0) s2[b * LL + l0 + l] = s;
  }

  // ---- coalesced store to aT ----
  unsigned short* dst = aT + (size_t)b * DD * LL + l0;
  #pragma unroll
  for (int idx = t; idx < 4096; idx += 1024) {
    int e = idx >> 4, ch = idx & 15;
    ushort4 v = *(const ushort4*)&sAT[e * 68 + ch * 4];
    *(ushort4*)(dst + (size_t)e * LL + ch * 4) = v;
  }
}

// ---------------------------------------------------------------------------
// attn: block = (b, 16 n-rows), 1024 thr = 16 waves (4/SIMD).
//  softmax: wave w -> row w.  PV MFMA: wave = e-quadrant (w&3) x l-quarter
//  (w>>2), ctxp[4] partials.  LN sums partials.  XCD swizzle (b&7).
// ---------------------------------------------------------------------------
__global__ __launch_bounds__(1024) void attn_kernel(
    const unsigned short* __restrict__ aT, const float* __restrict__ mol,
    const float* __restrict__ v1c, const float* __restrict__ s2,
    const float* __restrict__ amask, const float* __restrict__ smask,
    const float* __restrict__ gamma, const float* __restrict__ beta,
    float* __restrict__ out) {
  __shared__ unsigned short sattn[16 * 1024];  // 32 KB, XOR-swizzled
  __shared__ float ctxp[4][16][DD];            // 64 KB
  __shared__ float v1s[256];
  __shared__ float s1s[16];
  __shared__ float mu_s[16], rs_s[16];
  int i = blockIdx.x;
  int x = i & 7, k = i >> 3;
  int b = x + 8 * (k >> 4);
  int n0 = (k & 15) * 16;
  int t = threadIdx.x, w = t >> 6, lane = t & 63;

  float c0 = v1c[256];
  if (t < 256) v1s[t] = v1c[t];
  __syncthreads();

  // ---- s1: wave w -> row w (one float4 per lane, full-wave reduce) ----
  {
    const float* mr = mol + (size_t)(b * NN + n0 + w) * DD + lane * 4;
    float4 f = *(const float4*)mr;
    float s = f.x * v1s[lane * 4] + f.y * v1s[lane * 4 + 1] +
              f.z * v1s[lane * 4 + 2] + f.w * v1s[lane * 4 + 3];
    #pragma unroll
    for (int off = 32; off > 0; off >>= 1) s += __shfl_xor(s, off, 64);
    if (lane == 0) s1s[w] = s + c0;
  }
  __syncthreads();

  // ---- softmax: wave w -> row w ----
  {
    int r = w;
    float s1v = s1s[r];
    float p[16], amv[16];
    float mx = -INFINITY;
    #pragma unroll
    for (int q = 0; q < 16; ++q) {
      int l = lane + 64 * q;
      float sc = s1v + s2[b * LL + l];
      sc = sc > 0.f ? sc : NEG_SLOPE * sc;
      sc += smask[b * LL + l];
      amv[q] = amask[b * LL + l];
      p[q] = sc;
      mx = fmaxf(mx, sc);
    }
    #pragma unroll
    for (int off = 32; off > 0; off >>= 1) mx = fmaxf(mx, __shfl_xor(mx, off, 64));
    float sum = 0.f;
    #pragma unroll
    for (int q = 0; q < 16; ++q) {
      p[q] = __expf(p[q] - mx);
      sum += p[q];
    }
    #pragma unroll
    for (int off = 32; off > 0; off >>= 1) sum += __shfl_xor(sum, off, 64);
    float inv = 1.f / sum;
    #pragma unroll
    for (int q = 0; q < 16; ++q) {
      unsigned short bv = f2bf(p[q] * amv[q] * inv);
      int l = lane + 64 * q;
      int byte = ((r * 1024 + l) * 2) ^ ((r & 7) << 4);
      *(unsigned short*)((char*)sattn + byte) = bv;
    }
  }
  __syncthreads();

  // ---- PV MFMA: wave = e-quadrant (w&3) x l-quarter (w>>2) ----
  int lo16 = lane & 15, g = lane >> 4;
  int e0 = (w & 3) * 64, lq = w >> 2;
  f32x4 acc[4];
  #pragma unroll
  for (int n = 0; n < 4; ++n) acc[n] = f32x4{0.f, 0.f, 0.f, 0.f};
  const unsigned short* Bp =
      aT + (size_t)b * DD * LL + (size_t)(e0 + lo16) * LL + lq * 256 + g * 8;
  #pragma unroll 4
  for (int kk = 0; kk < 8; ++kk) {
    short8 afr = *(const short8*)((const char*)sattn +
        (((lo16 * 1024 + lq * 256 + kk * 32 + g * 8) * 2) ^ ((lo16 & 7) << 4)));
    #pragma unroll
    for (int n = 0; n < 4; ++n) {
      short8 bfr = *(const short8*)(Bp + (size_t)n * 16 * LL + kk * 32);
      acc[n] = __builtin_amdgcn_mfma_f32_16x16x32_bf16(afr, bfr, acc[n], 0, 0, 0);
    }
  }
  #pragma unroll
  for (int n = 0; n < 4; ++n)
    #pragma unroll
    for (int j = 0; j < 4; ++j)
      ctxp[lq][g * 4 + j][e0 + n * 16 + lo16] = acc[n][j];
  __syncthreads();

  // ---- LN stats: wave w -> row w ----
  {
    int r = w;
    float s = 0.f, sq = 0.f;
    #pragma unroll
    for (int jj = 0; jj < 4; ++jj) {
      int cc = lane + 64 * jj;
      float v = ctxp[0][r][cc] + ctxp[1][r][cc] + ctxp[2][r][cc] + ctxp[3][r][cc];
      s += v;
      sq += v * v;
    }
    #pragma unroll
    for (int off = 32; off > 0; off >>= 1) {
      s += __shfl_xor(s, off, 64);
      sq += __shfl_xor(sq, off, 64);
    }
    if (lane == 0) {
      float mu = s * (1.f / 256.f);
      float var = sq * (1.f / 256.f) - mu * mu;
      mu_s[r] = mu;
      rs_s[r] = rsqrtf(var + LN_EPS);
    }
  }
  __syncthreads();

  // ---- store ----
  #pragma unroll
  for (int q = 0; q < 4; ++q) {
    int idx = t + 1024 * q;
    int r = idx >> 8, d = idx & 255;
    float v = ctxp[0][r][d] + ctxp[1][r][d] + ctxp[2][r][d] + ctxp[3][r][d];
    out[(size_t)(b * NN + n0 + r) * DD + d] =
        (v - mu_s[r]) * rs_s[r] * gamma[d] + beta[d];
  }
}

// ---------------------------------------------------------------------------
extern "C" void kernel_launch(void* const* d_in, const int* in_sizes, int n_in,
                              void* d_out, int out_size, void* d_ws, size_t ws_size,
                              hipStream_t stream) {
  const float* mol     = (const float*)d_in[0];
  const float* atom    = (const float*)d_in[1];
  const float* amask   = (const float*)d_in[2];
  const float* smask   = (const float*)d_in[3];
  const float* W_mol   = (const float*)d_in[4];
  const float* b_mol   = (const float*)d_in[5];
  const float* W_nb    = (const float*)d_in[6];
  const float* b_nb    = (const float*)d_in[7];
  const float* align_w = (const float*)d_in[8];
  const float* align_b = (const float*)d_in[9];
  const float* gamma   = (const float*)d_in[10];
  const float* beta    = (const float*)d_in[11];
  float* outp = (float*)d_out;

  char* wsb = (char*)d_ws;
  unsigned short* aT = (unsigned short*)wsb;          // 8 MB
  float* s2  = (float*)(wsb + 8388608);               // 64 KB
  float* v1c = s2 + BB * LL;                          // 257 floats

  agemm_kernel<<<256, 1024, 0, stream>>>(atom, W_nb, b_nb, W_mol, b_mol,
                                         align_w, align_b, aT, s2, v1c);
  attn_kernel<<<256, 1024, 0, stream>>>(aT, mol, v1c, s2, amask, smask,
                                        gamma, beta, outp);
}